// Round 1
// baseline (446.228 us; speedup 1.0000x reference)
//
#include <hip/hip_runtime.h>
#include <hip/hip_bf16.h>
#include <cstdint>
#include <cstddef>

typedef __attribute__((ext_vector_type(8))) short bf16x8;
typedef __attribute__((ext_vector_type(8))) unsigned short ushort8;
typedef __attribute__((ext_vector_type(4))) float f32x4;

#define B_ 8
#define S_ 1024
#define E_ 1024
#define H_ 16
#define D_ 64

__device__ __forceinline__ unsigned short f2bf(float f) {
    union { float fp; unsigned int u; } v; v.fp = f;
    unsigned int u = v.u;
    return (unsigned short)((u + 0x7fffu + ((u >> 16) & 1u)) >> 16);
}

// ---------------- weight transpose-convert: W[K][N] f32 -> Wt[N][K] bf16 ----
__global__ __launch_bounds__(256) void wtrans(const float* __restrict__ W,
                                              unsigned short* __restrict__ Wt) {
    __shared__ float tile[32][33];
    const int k0 = blockIdx.y * 32, n0 = blockIdx.x * 32;
    const int tx = threadIdx.x & 31, ty = threadIdx.x >> 5;  // ty 0..7
#pragma unroll
    for (int i = ty; i < 32; i += 8)
        tile[i][tx] = W[(size_t)(k0 + i) * E_ + n0 + tx];
    __syncthreads();
#pragma unroll
    for (int i = ty; i < 32; i += 8)
        Wt[(size_t)(n0 + i) * E_ + k0 + tx] = f2bf(tile[tx][i]);
}

// ---------------- mask dtype detection: 1 = int32, 0 = byte/bool ------------
__global__ void detect_kernel(const unsigned int* __restrict__ m, int* __restrict__ flag) {
    unsigned int bad = 0;
    for (int i = threadIdx.x; i < 4096; i += 64) bad |= (m[i] > 1u) ? 1u : 0u;
    unsigned long long anybad = __ballot(bad != 0u);
    if (threadIdx.x == 0) *flag = (anybad == 0ull) ? 1 : 0;
}

// ---------------- GEMM: C[M][N] = A[M][K] @ Bt[N][K]^T ----------------------
// AMODE 0: A is f32 (convert on the fly). 1: A is bf16.
// EPI 0: write bf16 [B,H,S,D]   (QK projections)
// EPI 2: write bf16 [B,H,D,S]   (V transposed)
// EPI 3: write f32 row-major + residual (output projection)
template <int AMODE, int EPI>
__global__ __launch_bounds__(256) void gemm_bt(const void* __restrict__ Ap,
                                               const unsigned short* __restrict__ Bt,
                                               void* __restrict__ Cp,
                                               const float* __restrict__ resid) {
    __shared__ unsigned short As[128 * 40];  // 32 k padded to 40 (2-way = free)
    __shared__ unsigned short Bs[128 * 40];
    const int t = threadIdx.x;
    const int lane = t & 63, w = t >> 6;
    const int wr = w >> 1, wc = w & 1;
    const int l15 = lane & 15, l4 = lane >> 4;
    const int m0 = blockIdx.x * 128;
    const int n0 = blockIdx.y * 128;
    const int srow = t >> 1, shalf = t & 1;

    f32x4 acc[4][4];
#pragma unroll
    for (int i = 0; i < 4; ++i)
#pragma unroll
        for (int j = 0; j < 4; ++j) acc[i][j] = (f32x4){0.f, 0.f, 0.f, 0.f};

    for (int kt = 0; kt < E_; kt += 32) {
        if (AMODE == 0) {
            const float* Ag = (const float*)Ap + (size_t)(m0 + srow) * E_ + kt + shalf * 16;
            float4 f0 = ((const float4*)Ag)[0];
            float4 f1 = ((const float4*)Ag)[1];
            float4 f2 = ((const float4*)Ag)[2];
            float4 f3 = ((const float4*)Ag)[3];
            ushort8 o0, o1;
            o0[0] = f2bf(f0.x); o0[1] = f2bf(f0.y); o0[2] = f2bf(f0.z); o0[3] = f2bf(f0.w);
            o0[4] = f2bf(f1.x); o0[5] = f2bf(f1.y); o0[6] = f2bf(f1.z); o0[7] = f2bf(f1.w);
            o1[0] = f2bf(f2.x); o1[1] = f2bf(f2.y); o1[2] = f2bf(f2.z); o1[3] = f2bf(f2.w);
            o1[4] = f2bf(f3.x); o1[5] = f2bf(f3.y); o1[6] = f2bf(f3.z); o1[7] = f2bf(f3.w);
            *(ushort8*)&As[srow * 40 + shalf * 16] = o0;
            *(ushort8*)&As[srow * 40 + shalf * 16 + 8] = o1;
        } else {
            const unsigned short* Ag =
                (const unsigned short*)Ap + (size_t)(m0 + srow) * E_ + kt + shalf * 16;
            *(ushort8*)&As[srow * 40 + shalf * 16] = *(const ushort8*)Ag;
            *(ushort8*)&As[srow * 40 + shalf * 16 + 8] = *(const ushort8*)(Ag + 8);
        }
        {
            const unsigned short* Bg = Bt + (size_t)(n0 + srow) * E_ + kt + shalf * 16;
            *(ushort8*)&Bs[srow * 40 + shalf * 16] = *(const ushort8*)Bg;
            *(ushort8*)&Bs[srow * 40 + shalf * 16 + 8] = *(const ushort8*)(Bg + 8);
        }
        __syncthreads();
        bf16x8 af[4], bfv[4];
#pragma unroll
        for (int mi = 0; mi < 4; ++mi)
            af[mi] = *(const bf16x8*)&As[(wr * 64 + mi * 16 + l15) * 40 + l4 * 8];
#pragma unroll
        for (int ni = 0; ni < 4; ++ni)
            bfv[ni] = *(const bf16x8*)&Bs[(wc * 64 + ni * 16 + l15) * 40 + l4 * 8];
#pragma unroll
        for (int mi = 0; mi < 4; ++mi)
#pragma unroll
            for (int ni = 0; ni < 4; ++ni)
                acc[mi][ni] =
                    __builtin_amdgcn_mfma_f32_16x16x32_bf16(af[mi], bfv[ni], acc[mi][ni], 0, 0, 0);
        __syncthreads();
    }
#pragma unroll
    for (int mi = 0; mi < 4; ++mi) {
#pragma unroll
        for (int ni = 0; ni < 4; ++ni) {
#pragma unroll
            for (int r = 0; r < 4; ++r) {
                const int m = m0 + wr * 64 + mi * 16 + l4 * 4 + r;
                const int n = n0 + wc * 64 + ni * 16 + l15;
                const float v = acc[mi][ni][r];
                if (EPI == 0) {
                    const int b = m >> 10, s = m & 1023, h = n >> 6, d = n & 63;
                    ((unsigned short*)Cp)[(((size_t)b * H_ + h) * S_ + s) * D_ + d] = f2bf(v);
                } else if (EPI == 2) {
                    const int b = m >> 10, s = m & 1023, h = n >> 6, d = n & 63;
                    ((unsigned short*)Cp)[(((size_t)b * H_ + h) * D_ + d) * S_ + s] = f2bf(v);
                } else {
                    const size_t idx = (size_t)m * E_ + n;
                    ((float*)Cp)[idx] = v + resid[idx];
                }
            }
        }
    }
}

// ---------------- flash attention -------------------------------------------
// grid: (S/64, B*H). 4 waves, wave w owns Q rows q0+w*16 .. +15.
__global__ __launch_bounds__(256) void attn_kernel(const unsigned short* __restrict__ Qh,
                                                   const unsigned short* __restrict__ Kh,
                                                   const unsigned short* __restrict__ Vt,
                                                   const void* __restrict__ maskp,
                                                   const int* __restrict__ flagp,
                                                   unsigned short* __restrict__ degree) {
    __shared__ unsigned short Ks[64 * 64];
    __shared__ unsigned short Vs[64 * 64];
    __shared__ unsigned short Ps[4 * 16 * 64];
    const int t = threadIdx.x;
    const int lane = t & 63, w = t >> 6;
    const int l15 = lane & 15, l4 = lane >> 4;
    const int bh = blockIdx.y, b = bh >> 4, h = bh & 15;
    const int q0 = blockIdx.x * 64;
    const int mask32 = *flagp;
    const int* mi32 = (const int*)maskp;
    const unsigned char* mi8 = (const unsigned char*)maskp;

    bf16x8 qf[2];
    {
        const unsigned short* qptr =
            Qh + ((size_t)bh * S_ + q0 + w * 16 + l15) * D_ + l4 * 8;
        qf[0] = *(const bf16x8*)qptr;
        qf[1] = *(const bf16x8*)(qptr + 32);
    }
    f32x4 O[4];
#pragma unroll
    for (int i = 0; i < 4; ++i) O[i] = (f32x4){0.f, 0.f, 0.f, 0.f};
    float mrun[4] = {-3e38f, -3e38f, -3e38f, -3e38f};
    float lrun[4] = {0.f, 0.f, 0.f, 0.f};

    const int srow = t >> 2, sch = (t & 3) * 2;
    const int ssw = (srow & 7) << 4;
    char* KsB = (char*)Ks;
    char* VsB = (char*)Vs;
    char* PsB = (char*)Ps + w * 2048;

    for (int jt = 0; jt < S_; jt += 64) {
        {
            const unsigned short* kg =
                Kh + ((size_t)bh * S_ + jt + srow) * D_ + sch * 8;
            *(ushort8*)(KsB + srow * 128 + ((sch * 16) ^ ssw)) = *(const ushort8*)kg;
            *(ushort8*)(KsB + srow * 128 + ((sch * 16 + 16) ^ ssw)) = *(const ushort8*)(kg + 8);
            const unsigned short* vg =
                Vt + ((size_t)bh * D_ + srow) * S_ + jt + sch * 8;
            *(ushort8*)(VsB + srow * 128 + ((sch * 16) ^ ssw)) = *(const ushort8*)vg;
            *(ushort8*)(VsB + srow * 128 + ((sch * 16 + 16) ^ ssw)) = *(const ushort8*)(vg + 8);
        }
        __syncthreads();

        f32x4 sacc[4];
#pragma unroll
        for (int i = 0; i < 4; ++i) sacc[i] = (f32x4){0.f, 0.f, 0.f, 0.f};
#pragma unroll
        for (int ni = 0; ni < 4; ++ni) {
            const int row = l15 + ni * 16;
            const int sw = (row & 7) << 4;
            bf16x8 b0 = *(const bf16x8*)(KsB + row * 128 + ((l4 * 16) ^ sw));
            bf16x8 b1 = *(const bf16x8*)(KsB + row * 128 + ((64 + l4 * 16) ^ sw));
            sacc[ni] = __builtin_amdgcn_mfma_f32_16x16x32_bf16(qf[0], b0, sacc[ni], 0, 0, 0);
            sacc[ni] = __builtin_amdgcn_mfma_f32_16x16x32_bf16(qf[1], b1, sacc[ni], 0, 0, 0);
        }

        float pv[4][4];
#pragma unroll
        for (int r = 0; r < 4; ++r) {
            const int gr = q0 + w * 16 + l4 * 4 + r;
            const size_t mbase = ((size_t)b * S_ + gr) * S_ + jt;
            float rowmax = -3e38f;
#pragma unroll
            for (int ni = 0; ni < 4; ++ni) {
                const int gc = l15 + ni * 16;
                const bool msk = mask32 ? (mi32[mbase + gc] != 0) : (mi8[mbase + gc] != 0);
                const float s = msk ? -1e9f : sacc[ni][r] * 0.125f;
                pv[ni][r] = s;
                rowmax = fmaxf(rowmax, s);
            }
#pragma unroll
            for (int off = 1; off < 16; off <<= 1)
                rowmax = fmaxf(rowmax, __shfl_xor(rowmax, off, 64));
            const float mnew = fmaxf(mrun[r], rowmax);
            const float corr = __expf(mrun[r] - mnew);
            float ps = 0.f;
#pragma unroll
            for (int ni = 0; ni < 4; ++ni) {
                const float p = __expf(pv[ni][r] - mnew);
                pv[ni][r] = p;
                ps += p;
            }
#pragma unroll
            for (int off = 1; off < 16; off <<= 1) ps += __shfl_xor(ps, off, 64);
            lrun[r] = lrun[r] * corr + ps;
            mrun[r] = mnew;
#pragma unroll
            for (int df = 0; df < 4; ++df) O[df][r] *= corr;
        }

#pragma unroll
        for (int r = 0; r < 4; ++r) {
            const int row = l4 * 4 + r;
            const int sw = (row & 7) << 4;
#pragma unroll
            for (int ni = 0; ni < 4; ++ni) {
                const int col = l15 + ni * 16;
                *(unsigned short*)(PsB + row * 128 + ((col * 2) ^ sw)) = f2bf(pv[ni][r]);
            }
        }
        asm volatile("s_waitcnt lgkmcnt(0)" ::: "memory");
        bf16x8 pa[2];
        {
            const int row = l15;
            const int sw = (row & 7) << 4;
            pa[0] = *(const bf16x8*)(PsB + row * 128 + ((l4 * 16) ^ sw));
            pa[1] = *(const bf16x8*)(PsB + row * 128 + ((64 + l4 * 16) ^ sw));
        }
#pragma unroll
        for (int df = 0; df < 4; ++df) {
            const int row = l15 + df * 16;
            const int sw = (row & 7) << 4;
            bf16x8 v0 = *(const bf16x8*)(VsB + row * 128 + ((l4 * 16) ^ sw));
            bf16x8 v1 = *(const bf16x8*)(VsB + row * 128 + ((64 + l4 * 16) ^ sw));
            O[df] = __builtin_amdgcn_mfma_f32_16x16x32_bf16(pa[0], v0, O[df], 0, 0, 0);
            O[df] = __builtin_amdgcn_mfma_f32_16x16x32_bf16(pa[1], v1, O[df], 0, 0, 0);
        }
        __syncthreads();
    }

#pragma unroll
    for (int r = 0; r < 4; ++r) {
        const float inv = 1.f / lrun[r];
#pragma unroll
        for (int df = 0; df < 4; ++df) {
            const size_t dst = ((size_t)b * S_ + q0 + w * 16 + l4 * 4 + r) * (size_t)(H_ * D_) +
                               h * 64 + df * 16 + l15;
            degree[dst] = f2bf(O[df][r] * inv);
        }
    }
}

// ---------------- in-place row LayerNorm over E=1024 ------------------------
__global__ __launch_bounds__(256) void lnorm(float* __restrict__ io,
                                             const float* __restrict__ gamma,
                                             const float* __restrict__ beta) {
    const int row = blockIdx.x;
    const int t = threadIdx.x;
    float4 v = ((const float4*)(io + (size_t)row * E_))[t];
    float s = v.x + v.y + v.z + v.w;
    float q = v.x * v.x + v.y * v.y + v.z * v.z + v.w * v.w;
#pragma unroll
    for (int off = 32; off; off >>= 1) {
        s += __shfl_down(s, off, 64);
        q += __shfl_down(q, off, 64);
    }
    __shared__ float red[8];
    const int wid = t >> 6;
    if ((t & 63) == 0) { red[wid] = s; red[4 + wid] = q; }
    __syncthreads();
    const float ts = red[0] + red[1] + red[2] + red[3];
    const float tq = red[4] + red[5] + red[6] + red[7];
    const float mean = ts * (1.0f / E_);
    const float var = tq * (1.0f / E_) - mean * mean;
    const float rstd = rsqrtf(var + 1e-5f);
    const float4 g = ((const float4*)gamma)[t];
    const float4 bb = ((const float4*)beta)[t];
    v.x = (v.x - mean) * rstd * g.x + bb.x;
    v.y = (v.y - mean) * rstd * g.y + bb.y;
    v.z = (v.z - mean) * rstd * g.z + bb.z;
    v.w = (v.w - mean) * rstd * g.w + bb.w;
    ((float4*)(io + (size_t)row * E_))[t] = v;
}

extern "C" void kernel_launch(void* const* d_in, const int* in_sizes, int n_in,
                              void* d_out, int out_size, void* d_ws, size_t ws_size,
                              hipStream_t stream) {
    const float* query = (const float*)d_in[0];
    const float* key_ = (const float*)d_in[1];
    const float* value = (const float*)d_in[2];
    const void* maskp = d_in[3];
    const float* Wq = (const float*)d_in[4];
    const float* Wk = (const float*)d_in[5];
    const float* Wv = (const float*)d_in[6];
    const float* Wo = (const float*)d_in[7];
    const float* gamma = (const float*)d_in[8];
    const float* beta = (const float*)d_in[9];
    float* out = (float*)d_out;
    char* ws = (char*)d_ws;
    const size_t MB = 1024ull * 1024ull;

    unsigned short* WqT = (unsigned short*)(ws + 0 * MB);
    unsigned short* WkT = (unsigned short*)(ws + 2 * MB);
    unsigned short* WvT = (unsigned short*)(ws + 4 * MB);
    unsigned short* WoT = (unsigned short*)(ws + 6 * MB);
    unsigned short* Qh = (unsigned short*)(ws + 8 * MB);   // [B,H,S,D] bf16 16MB
    unsigned short* Kh = (unsigned short*)(ws + 24 * MB);  // [B,H,S,D] bf16 16MB
    unsigned short* Vt = (unsigned short*)(ws + 40 * MB);  // [B,H,D,S] bf16 16MB
    unsigned short* deg = (unsigned short*)(ws + 56 * MB); // [B,S,H*D] bf16 16MB
    int* flag = (int*)(ws + 72 * MB);

    wtrans<<<dim3(32, 32), 256, 0, stream>>>(Wq, WqT);
    wtrans<<<dim3(32, 32), 256, 0, stream>>>(Wk, WkT);
    wtrans<<<dim3(32, 32), 256, 0, stream>>>(Wv, WvT);
    wtrans<<<dim3(32, 32), 256, 0, stream>>>(Wo, WoT);
    detect_kernel<<<1, 64, 0, stream>>>((const unsigned int*)maskp, flag);

    gemm_bt<0, 0><<<dim3(64, 8), 256, 0, stream>>>(query, WqT, Qh, nullptr);
    gemm_bt<0, 0><<<dim3(64, 8), 256, 0, stream>>>(key_, WkT, Kh, nullptr);
    gemm_bt<0, 2><<<dim3(64, 8), 256, 0, stream>>>(value, WvT, Vt, nullptr);

    attn_kernel<<<dim3(16, 128), 256, 0, stream>>>(Qh, Kh, Vt, maskp, flag, deg);

    gemm_bt<1, 3><<<dim3(64, 8), 256, 0, stream>>>(deg, WoT, out, query);
    lnorm<<<8192, 256, 0, stream>>>(out, gamma, beta);
}

// Round 2
// 341.322 us; speedup vs baseline: 1.3074x; 1.3074x over previous
//
#include <hip/hip_runtime.h>
#include <hip/hip_bf16.h>
#include <cstdint>
#include <cstddef>

typedef __attribute__((ext_vector_type(8))) short bf16x8;
typedef __attribute__((ext_vector_type(8))) unsigned short ushort8;
typedef __attribute__((ext_vector_type(4))) float f32x4;

#define B_ 8
#define S_ 1024
#define E_ 1024
#define H_ 16
#define D_ 64
#define NW_ (S_ / 64)  // mask words per row

__device__ __forceinline__ unsigned short f2bf(float f) {
    union { float fp; unsigned int u; } v; v.fp = f;
    unsigned int u = v.u;
    return (unsigned short)((u + 0x7fffu + ((u >> 16) & 1u)) >> 16);
}

// ---------------- weight transpose-convert: W[K][N] f32 -> Wt[N][K] bf16 ----
__global__ __launch_bounds__(256) void wtrans(const float* __restrict__ W,
                                              unsigned short* __restrict__ Wt) {
    __shared__ float tile[32][33];
    const int k0 = blockIdx.y * 32, n0 = blockIdx.x * 32;
    const int tx = threadIdx.x & 31, ty = threadIdx.x >> 5;  // ty 0..7
#pragma unroll
    for (int i = ty; i < 32; i += 8)
        tile[i][tx] = W[(size_t)(k0 + i) * E_ + n0 + tx];
    __syncthreads();
#pragma unroll
    for (int i = ty; i < 32; i += 8)
        Wt[(size_t)(n0 + i) * E_ + k0 + tx] = f2bf(tile[tx][i]);
}

// ---------------- mask dtype detection: 1 = int32, 0 = byte/bool ------------
__global__ void detect_kernel(const unsigned int* __restrict__ m, int* __restrict__ flag) {
    unsigned int bad = 0;
    for (int i = threadIdx.x; i < 4096; i += 64) bad |= (m[i] > 1u) ? 1u : 0u;
    unsigned long long anybad = __ballot(bad != 0u);
    if (threadIdx.x == 0) *flag = (anybad == 0ull) ? 1 : 0;
}

// ---------------- mask bit-pack: bool/int32 -> uint64 bitmap ----------------
// word w covers mask elements [w*64 .. w*64+63]; bit i = (mask[w*64+i] != 0)
__global__ __launch_bounds__(256) void pack_mask(const void* __restrict__ maskp,
                                                 const int* __restrict__ flagp,
                                                 unsigned long long* __restrict__ mbits) {
    const int mask32 = *flagp;
    const int lane = threadIdx.x & 63;
    const int gw = blockIdx.x * 4 + (threadIdx.x >> 6);
    const int nwaves = gridDim.x * 4;
    const int totw = B_ * S_ * NW_;
    for (int w = gw; w < totw; w += nwaves) {
        bool m;
        if (mask32) m = ((const int*)maskp)[(size_t)w * 64 + lane] != 0;
        else        m = ((const unsigned char*)maskp)[(size_t)w * 64 + lane] != 0;
        unsigned long long bits = __ballot(m);
        if (lane == 0) mbits[w] = bits;
    }
}

// ---------------- GEMM: C[M][N] = A[M][K] @ Bt[N][K]^T ----------------------
// AMODE 0: A is f32 (convert on the fly). 1: A is bf16.
// EPI 0: write bf16 [B,H,S,D]   (QK projections)
// EPI 2: write bf16 [B,H,D,S]   (V transposed)
// EPI 3: write f32 row-major + residual (output projection)
template <int AMODE, int EPI>
__global__ __launch_bounds__(256) void gemm_bt(const void* __restrict__ Ap,
                                               const unsigned short* __restrict__ Bt,
                                               void* __restrict__ Cp,
                                               const float* __restrict__ resid) {
    __shared__ unsigned short As[128 * 40];  // 32 k padded to 40 (2-way = free)
    __shared__ unsigned short Bs[128 * 40];
    const int t = threadIdx.x;
    const int lane = t & 63, w = t >> 6;
    const int wr = w >> 1, wc = w & 1;
    const int l15 = lane & 15, l4 = lane >> 4;
    const int m0 = blockIdx.x * 128;
    const int n0 = blockIdx.y * 128;
    const int srow = t >> 1, shalf = t & 1;

    f32x4 acc[4][4];
#pragma unroll
    for (int i = 0; i < 4; ++i)
#pragma unroll
        for (int j = 0; j < 4; ++j) acc[i][j] = (f32x4){0.f, 0.f, 0.f, 0.f};

    for (int kt = 0; kt < E_; kt += 32) {
        if (AMODE == 0) {
            const float* Ag = (const float*)Ap + (size_t)(m0 + srow) * E_ + kt + shalf * 16;
            float4 f0 = ((const float4*)Ag)[0];
            float4 f1 = ((const float4*)Ag)[1];
            float4 f2 = ((const float4*)Ag)[2];
            float4 f3 = ((const float4*)Ag)[3];
            ushort8 o0, o1;
            o0[0] = f2bf(f0.x); o0[1] = f2bf(f0.y); o0[2] = f2bf(f0.z); o0[3] = f2bf(f0.w);
            o0[4] = f2bf(f1.x); o0[5] = f2bf(f1.y); o0[6] = f2bf(f1.z); o0[7] = f2bf(f1.w);
            o1[0] = f2bf(f2.x); o1[1] = f2bf(f2.y); o1[2] = f2bf(f2.z); o1[3] = f2bf(f2.w);
            o1[4] = f2bf(f3.x); o1[5] = f2bf(f3.y); o1[6] = f2bf(f3.z); o1[7] = f2bf(f3.w);
            *(ushort8*)&As[srow * 40 + shalf * 16] = o0;
            *(ushort8*)&As[srow * 40 + shalf * 16 + 8] = o1;
        } else {
            const unsigned short* Ag =
                (const unsigned short*)Ap + (size_t)(m0 + srow) * E_ + kt + shalf * 16;
            *(ushort8*)&As[srow * 40 + shalf * 16] = *(const ushort8*)Ag;
            *(ushort8*)&As[srow * 40 + shalf * 16 + 8] = *(const ushort8*)(Ag + 8);
        }
        {
            const unsigned short* Bg = Bt + (size_t)(n0 + srow) * E_ + kt + shalf * 16;
            *(ushort8*)&Bs[srow * 40 + shalf * 16] = *(const ushort8*)Bg;
            *(ushort8*)&Bs[srow * 40 + shalf * 16 + 8] = *(const ushort8*)(Bg + 8);
        }
        __syncthreads();
        bf16x8 af[4], bfv[4];
#pragma unroll
        for (int mi = 0; mi < 4; ++mi)
            af[mi] = *(const bf16x8*)&As[(wr * 64 + mi * 16 + l15) * 40 + l4 * 8];
#pragma unroll
        for (int ni = 0; ni < 4; ++ni)
            bfv[ni] = *(const bf16x8*)&Bs[(wc * 64 + ni * 16 + l15) * 40 + l4 * 8];
#pragma unroll
        for (int mi = 0; mi < 4; ++mi)
#pragma unroll
            for (int ni = 0; ni < 4; ++ni)
                acc[mi][ni] =
                    __builtin_amdgcn_mfma_f32_16x16x32_bf16(af[mi], bfv[ni], acc[mi][ni], 0, 0, 0);
        __syncthreads();
    }
#pragma unroll
    for (int mi = 0; mi < 4; ++mi) {
#pragma unroll
        for (int ni = 0; ni < 4; ++ni) {
#pragma unroll
            for (int r = 0; r < 4; ++r) {
                const int m = m0 + wr * 64 + mi * 16 + l4 * 4 + r;
                const int n = n0 + wc * 64 + ni * 16 + l15;
                const float v = acc[mi][ni][r];
                if (EPI == 0) {
                    const int b = m >> 10, s = m & 1023, h = n >> 6, d = n & 63;
                    ((unsigned short*)Cp)[(((size_t)b * H_ + h) * S_ + s) * D_ + d] = f2bf(v);
                } else if (EPI == 2) {
                    const int b = m >> 10, s = m & 1023, h = n >> 6, d = n & 63;
                    ((unsigned short*)Cp)[(((size_t)b * H_ + h) * D_ + d) * S_ + s] = f2bf(v);
                } else {
                    const size_t idx = (size_t)m * E_ + n;
                    ((float*)Cp)[idx] = v + resid[idx];
                }
            }
        }
    }
}

// ---------------- flash attention -------------------------------------------
// grid: (S/64, B*H). 4 waves, wave w owns Q rows q0+w*16 .. +15.
__global__ __launch_bounds__(256) void attn_kernel(const unsigned short* __restrict__ Qh,
                                                   const unsigned short* __restrict__ Kh,
                                                   const unsigned short* __restrict__ Vt,
                                                   const unsigned long long* __restrict__ mbits,
                                                   unsigned short* __restrict__ degree) {
    __shared__ unsigned short Ks[64 * 64];
    __shared__ unsigned short Vs[64 * 64];
    __shared__ unsigned short Ps[4 * 16 * 64];
    const int t = threadIdx.x;
    const int lane = t & 63, w = t >> 6;
    const int l15 = lane & 15, l4 = lane >> 4;
    const int bh = blockIdx.y, b = bh >> 4, h = bh & 15;
    const int q0 = blockIdx.x * 64;

    // per-lane mask row pointer: rows q0 + w*16 + l4*4 + r  (r = 0..3)
    const unsigned long long* mrow =
        mbits + ((size_t)b * S_ + q0 + w * 16 + l4 * 4) * NW_;

    bf16x8 qf[2];
    {
        const unsigned short* qptr =
            Qh + ((size_t)bh * S_ + q0 + w * 16 + l15) * D_ + l4 * 8;
        qf[0] = *(const bf16x8*)qptr;
        qf[1] = *(const bf16x8*)(qptr + 32);
    }
    f32x4 O[4];
#pragma unroll
    for (int i = 0; i < 4; ++i) O[i] = (f32x4){0.f, 0.f, 0.f, 0.f};
    float mrun[4] = {-3e38f, -3e38f, -3e38f, -3e38f};
    float lrun[4] = {0.f, 0.f, 0.f, 0.f};

    const int srow = t >> 2, sch = (t & 3) * 2;
    const int ssw = (srow & 7) << 4;
    char* KsB = (char*)Ks;
    char* VsB = (char*)Vs;
    char* PsB = (char*)Ps + w * 2048;

    for (int jt = 0; jt < S_; jt += 64) {
        {
            const unsigned short* kg =
                Kh + ((size_t)bh * S_ + jt + srow) * D_ + sch * 8;
            *(ushort8*)(KsB + srow * 128 + ((sch * 16) ^ ssw)) = *(const ushort8*)kg;
            *(ushort8*)(KsB + srow * 128 + ((sch * 16 + 16) ^ ssw)) = *(const ushort8*)(kg + 8);
            const unsigned short* vg =
                Vt + ((size_t)bh * D_ + srow) * S_ + jt + sch * 8;
            *(ushort8*)(VsB + srow * 128 + ((sch * 16) ^ ssw)) = *(const ushort8*)vg;
            *(ushort8*)(VsB + srow * 128 + ((sch * 16 + 16) ^ ssw)) = *(const ushort8*)(vg + 8);
        }
        // issue mask-word loads early so they overlap the QK^T MFMAs
        const int mw_idx = jt >> 6;
        unsigned long long mw0 = mrow[0 * NW_ + mw_idx];
        unsigned long long mw1 = mrow[1 * NW_ + mw_idx];
        unsigned long long mw2 = mrow[2 * NW_ + mw_idx];
        unsigned long long mw3 = mrow[3 * NW_ + mw_idx];
        __syncthreads();

        f32x4 sacc[4];
#pragma unroll
        for (int i = 0; i < 4; ++i) sacc[i] = (f32x4){0.f, 0.f, 0.f, 0.f};
#pragma unroll
        for (int ni = 0; ni < 4; ++ni) {
            const int row = l15 + ni * 16;
            const int sw = (row & 7) << 4;
            bf16x8 b0 = *(const bf16x8*)(KsB + row * 128 + ((l4 * 16) ^ sw));
            bf16x8 b1 = *(const bf16x8*)(KsB + row * 128 + ((64 + l4 * 16) ^ sw));
            sacc[ni] = __builtin_amdgcn_mfma_f32_16x16x32_bf16(qf[0], b0, sacc[ni], 0, 0, 0);
            sacc[ni] = __builtin_amdgcn_mfma_f32_16x16x32_bf16(qf[1], b1, sacc[ni], 0, 0, 0);
        }

        float pv[4][4];
        unsigned long long mwr[4] = {mw0, mw1, mw2, mw3};
#pragma unroll
        for (int r = 0; r < 4; ++r) {
            const unsigned long long mw = mwr[r];
            float rowmax = -3e38f;
#pragma unroll
            for (int ni = 0; ni < 4; ++ni) {
                const int gc = l15 + ni * 16;
                const bool msk = (mw >> gc) & 1ull;
                const float s = msk ? -1e9f : sacc[ni][r] * 0.125f;
                pv[ni][r] = s;
                rowmax = fmaxf(rowmax, s);
            }
#pragma unroll
            for (int off = 1; off < 16; off <<= 1)
                rowmax = fmaxf(rowmax, __shfl_xor(rowmax, off, 64));
            const float mnew = fmaxf(mrun[r], rowmax);
            const float corr = __expf(mrun[r] - mnew);
            float ps = 0.f;
#pragma unroll
            for (int ni = 0; ni < 4; ++ni) {
                const float p = __expf(pv[ni][r] - mnew);
                pv[ni][r] = p;
                ps += p;
            }
#pragma unroll
            for (int off = 1; off < 16; off <<= 1) ps += __shfl_xor(ps, off, 64);
            lrun[r] = lrun[r] * corr + ps;
            mrun[r] = mnew;
#pragma unroll
            for (int df = 0; df < 4; ++df) O[df][r] *= corr;
        }

#pragma unroll
        for (int r = 0; r < 4; ++r) {
            const int row = l4 * 4 + r;
            const int sw = (row & 7) << 4;
#pragma unroll
            for (int ni = 0; ni < 4; ++ni) {
                const int col = l15 + ni * 16;
                *(unsigned short*)(PsB + row * 128 + ((col * 2) ^ sw)) = f2bf(pv[ni][r]);
            }
        }
        asm volatile("s_waitcnt lgkmcnt(0)" ::: "memory");
        bf16x8 pa[2];
        {
            const int row = l15;
            const int sw = (row & 7) << 4;
            pa[0] = *(const bf16x8*)(PsB + row * 128 + ((l4 * 16) ^ sw));
            pa[1] = *(const bf16x8*)(PsB + row * 128 + ((64 + l4 * 16) ^ sw));
        }
#pragma unroll
        for (int df = 0; df < 4; ++df) {
            const int row = l15 + df * 16;
            const int sw = (row & 7) << 4;
            bf16x8 v0 = *(const bf16x8*)(VsB + row * 128 + ((l4 * 16) ^ sw));
            bf16x8 v1 = *(const bf16x8*)(VsB + row * 128 + ((64 + l4 * 16) ^ sw));
            O[df] = __builtin_amdgcn_mfma_f32_16x16x32_bf16(pa[0], v0, O[df], 0, 0, 0);
            O[df] = __builtin_amdgcn_mfma_f32_16x16x32_bf16(pa[1], v1, O[df], 0, 0, 0);
        }
        __syncthreads();
    }

#pragma unroll
    for (int r = 0; r < 4; ++r) {
        const float inv = 1.f / lrun[r];
#pragma unroll
        for (int df = 0; df < 4; ++df) {
            const size_t dst = ((size_t)b * S_ + q0 + w * 16 + l4 * 4 + r) * (size_t)(H_ * D_) +
                               h * 64 + df * 16 + l15;
            degree[dst] = f2bf(O[df][r] * inv);
        }
    }
}

// ---------------- in-place row LayerNorm over E=1024 ------------------------
__global__ __launch_bounds__(256) void lnorm(float* __restrict__ io,
                                             const float* __restrict__ gamma,
                                             const float* __restrict__ beta) {
    const int row = blockIdx.x;
    const int t = threadIdx.x;
    float4 v = ((const float4*)(io + (size_t)row * E_))[t];
    float s = v.x + v.y + v.z + v.w;
    float q = v.x * v.x + v.y * v.y + v.z * v.z + v.w * v.w;
#pragma unroll
    for (int off = 32; off; off >>= 1) {
        s += __shfl_down(s, off, 64);
        q += __shfl_down(q, off, 64);
    }
    __shared__ float red[8];
    const int wid = t >> 6;
    if ((t & 63) == 0) { red[wid] = s; red[4 + wid] = q; }
    __syncthreads();
    const float ts = red[0] + red[1] + red[2] + red[3];
    const float tq = red[4] + red[5] + red[6] + red[7];
    const float mean = ts * (1.0f / E_);
    const float var = tq * (1.0f / E_) - mean * mean;
    const float rstd = rsqrtf(var + 1e-5f);
    const float4 g = ((const float4*)gamma)[t];
    const float4 bb = ((const float4*)beta)[t];
    v.x = (v.x - mean) * rstd * g.x + bb.x;
    v.y = (v.y - mean) * rstd * g.y + bb.y;
    v.z = (v.z - mean) * rstd * g.z + bb.z;
    v.w = (v.w - mean) * rstd * g.w + bb.w;
    ((float4*)(io + (size_t)row * E_))[t] = v;
}

extern "C" void kernel_launch(void* const* d_in, const int* in_sizes, int n_in,
                              void* d_out, int out_size, void* d_ws, size_t ws_size,
                              hipStream_t stream) {
    const float* query = (const float*)d_in[0];
    const float* key_ = (const float*)d_in[1];
    const float* value = (const float*)d_in[2];
    const void* maskp = d_in[3];
    const float* Wq = (const float*)d_in[4];
    const float* Wk = (const float*)d_in[5];
    const float* Wv = (const float*)d_in[6];
    const float* Wo = (const float*)d_in[7];
    const float* gamma = (const float*)d_in[8];
    const float* beta = (const float*)d_in[9];
    float* out = (float*)d_out;
    char* ws = (char*)d_ws;
    const size_t MB = 1024ull * 1024ull;

    unsigned short* WqT = (unsigned short*)(ws + 0 * MB);
    unsigned short* WkT = (unsigned short*)(ws + 2 * MB);
    unsigned short* WvT = (unsigned short*)(ws + 4 * MB);
    unsigned short* WoT = (unsigned short*)(ws + 6 * MB);
    unsigned short* Qh = (unsigned short*)(ws + 8 * MB);   // [B,H,S,D] bf16 16MB
    unsigned short* Kh = (unsigned short*)(ws + 24 * MB);  // [B,H,S,D] bf16 16MB
    unsigned short* Vt = (unsigned short*)(ws + 40 * MB);  // [B,H,D,S] bf16 16MB
    unsigned short* deg = (unsigned short*)(ws + 56 * MB); // [B,S,H*D] bf16 16MB
    int* flag = (int*)(ws + 72 * MB);
    unsigned long long* mbits = (unsigned long long*)(ws + 72 * MB + 4096);  // 1MB

    wtrans<<<dim3(32, 32), 256, 0, stream>>>(Wq, WqT);
    wtrans<<<dim3(32, 32), 256, 0, stream>>>(Wk, WkT);
    wtrans<<<dim3(32, 32), 256, 0, stream>>>(Wv, WvT);
    wtrans<<<dim3(32, 32), 256, 0, stream>>>(Wo, WoT);
    detect_kernel<<<1, 64, 0, stream>>>((const unsigned int*)maskp, flag);
    pack_mask<<<2048, 256, 0, stream>>>(maskp, flag, mbits);

    gemm_bt<0, 0><<<dim3(64, 8), 256, 0, stream>>>(query, WqT, Qh, nullptr);
    gemm_bt<0, 0><<<dim3(64, 8), 256, 0, stream>>>(key_, WkT, Kh, nullptr);
    gemm_bt<0, 2><<<dim3(64, 8), 256, 0, stream>>>(value, WvT, Vt, nullptr);

    attn_kernel<<<dim3(16, 128), 256, 0, stream>>>(Qh, Kh, Vt, mbits, deg);

    gemm_bt<1, 3><<<dim3(64, 8), 256, 0, stream>>>(deg, WoT, out, query);
    lnorm<<<8192, 256, 0, stream>>>(out, gamma, beta);
}

// Round 3
// 300.255 us; speedup vs baseline: 1.4862x; 1.1368x over previous
//
#include <hip/hip_runtime.h>
#include <hip/hip_bf16.h>
#include <cstdint>
#include <cstddef>

typedef __attribute__((ext_vector_type(8))) short bf16x8;
typedef __attribute__((ext_vector_type(8))) unsigned short ushort8;
typedef __attribute__((ext_vector_type(4))) float f32x4;

#define B_ 8
#define S_ 1024
#define E_ 1024
#define H_ 16
#define D_ 64
#define NW_ (S_ / 64)  // mask words per row

__device__ __forceinline__ unsigned short f2bf(float f) {
    union { float fp; unsigned int u; } v; v.fp = f;
    unsigned int u = v.u;
    return (unsigned short)((u + 0x7fffu + ((u >> 16) & 1u)) >> 16);
}

__device__ __forceinline__ void gload16(const void* g, void* l) {
    __builtin_amdgcn_global_load_lds((__attribute__((address_space(1))) void*)g,
                                     (__attribute__((address_space(3))) void*)l,
                                     16, 0, 0);
}

// ---------------- f32 -> bf16 bulk convert ----------------------------------
__global__ __launch_bounds__(256) void f32_to_bf16(const float* __restrict__ in,
                                                   unsigned short* __restrict__ out,
                                                   int n8) {
    int i = blockIdx.x * 256 + threadIdx.x;
    const int stride = gridDim.x * 256;
    for (; i < n8; i += stride) {
        float4 f0 = ((const float4*)in)[i * 2];
        float4 f1 = ((const float4*)in)[i * 2 + 1];
        ushort8 o;
        o[0] = f2bf(f0.x); o[1] = f2bf(f0.y); o[2] = f2bf(f0.z); o[3] = f2bf(f0.w);
        o[4] = f2bf(f1.x); o[5] = f2bf(f1.y); o[6] = f2bf(f1.z); o[7] = f2bf(f1.w);
        ((ushort8*)out)[i] = o;
    }
}

// ---------------- weight transpose-convert: W[K][N] f32 -> Wt[N][K] bf16 ----
__global__ __launch_bounds__(256) void wtrans(const float* __restrict__ W,
                                              unsigned short* __restrict__ Wt) {
    __shared__ float tile[32][33];
    const int k0 = blockIdx.y * 32, n0 = blockIdx.x * 32;
    const int tx = threadIdx.x & 31, ty = threadIdx.x >> 5;  // ty 0..7
#pragma unroll
    for (int i = ty; i < 32; i += 8)
        tile[i][tx] = W[(size_t)(k0 + i) * E_ + n0 + tx];
    __syncthreads();
#pragma unroll
    for (int i = ty; i < 32; i += 8)
        Wt[(size_t)(n0 + i) * E_ + k0 + tx] = f2bf(tile[tx][i]);
}

// ---------------- mask dtype detection: 1 = int32, 0 = byte/bool ------------
__global__ void detect_kernel(const unsigned int* __restrict__ m, int* __restrict__ flag) {
    unsigned int bad = 0;
    for (int i = threadIdx.x; i < 4096; i += 64) bad |= (m[i] > 1u) ? 1u : 0u;
    unsigned long long anybad = __ballot(bad != 0u);
    if (threadIdx.x == 0) *flag = (anybad == 0ull) ? 1 : 0;
}

// ---------------- mask bit-pack: bool/int32 -> uint64 bitmap ----------------
__global__ __launch_bounds__(256) void pack_mask(const void* __restrict__ maskp,
                                                 const int* __restrict__ flagp,
                                                 unsigned long long* __restrict__ mbits) {
    const int mask32 = *flagp;
    const int lane = threadIdx.x & 63;
    const int gw = blockIdx.x * 4 + (threadIdx.x >> 6);
    const int nwaves = gridDim.x * 4;
    const int totw = B_ * S_ * NW_;
    for (int w = gw; w < totw; w += nwaves) {
        bool m;
        if (mask32) m = ((const int*)maskp)[(size_t)w * 64 + lane] != 0;
        else        m = ((const unsigned char*)maskp)[(size_t)w * 64 + lane] != 0;
        unsigned long long bits = __ballot(m);
        if (lane == 0) mbits[w] = bits;
    }
}

// ---------------- GEMM (m97 structure): C = A[M][K] @ Bt[N][K]^T ------------
// A is bf16. Staging via global_load_lds width=16, linear LDS [128][32].
// EPI 0: write bf16 [B,H,S,D]; EPI 2: bf16 [B,H,D,S]; EPI 3: f32 + resid.
template <int EPI>
__global__ __launch_bounds__(256) void gemm_bt(const unsigned short* __restrict__ A,
                                               const unsigned short* __restrict__ Bt,
                                               void* __restrict__ Cp,
                                               const float* __restrict__ resid) {
    __shared__ unsigned short As[128 * 32];
    __shared__ unsigned short Bs[128 * 32];
    const int t = threadIdx.x;
    const int lane = t & 63, w = t >> 6;
    const int wr = w >> 1, wc = w & 1;
    const int l15 = lane & 15, l4 = lane >> 4;
    const int m0 = blockIdx.x * 128, n0 = blockIdx.y * 128;

    // staging: wave w owns rows [w*32, w*32+31]; each gload covers 16 rows.
    const int srow = w * 32 + (lane >> 2);
    const int scol = (lane & 3) * 8;
    const unsigned short* Ag0 = A + (size_t)(m0 + srow) * E_ + scol;
    const unsigned short* Ag1 = A + (size_t)(m0 + srow + 16) * E_ + scol;
    const unsigned short* Bg0 = Bt + (size_t)(n0 + srow) * E_ + scol;
    const unsigned short* Bg1 = Bt + (size_t)(n0 + srow + 16) * E_ + scol;
    unsigned short* Al = &As[w * 1024];        // wave-uniform LDS bases
    unsigned short* Bl = &Bs[w * 1024];

    f32x4 acc[4][4];
#pragma unroll
    for (int i = 0; i < 4; ++i)
#pragma unroll
        for (int j = 0; j < 4; ++j) acc[i][j] = (f32x4){0.f, 0.f, 0.f, 0.f};

    for (int kt = 0; kt < E_; kt += 32) {
        gload16(Ag0 + kt, Al);
        gload16(Ag1 + kt, Al + 512);
        gload16(Bg0 + kt, Bl);
        gload16(Bg1 + kt, Bl + 512);
        __syncthreads();
        bf16x8 af[4], bfv[4];
#pragma unroll
        for (int mi = 0; mi < 4; ++mi)
            af[mi] = *(const bf16x8*)&As[(wr * 64 + mi * 16 + l15) * 32 + l4 * 8];
#pragma unroll
        for (int ni = 0; ni < 4; ++ni)
            bfv[ni] = *(const bf16x8*)&Bs[(wc * 64 + ni * 16 + l15) * 32 + l4 * 8];
#pragma unroll
        for (int mi = 0; mi < 4; ++mi)
#pragma unroll
            for (int ni = 0; ni < 4; ++ni)
                acc[mi][ni] =
                    __builtin_amdgcn_mfma_f32_16x16x32_bf16(af[mi], bfv[ni], acc[mi][ni], 0, 0, 0);
        __syncthreads();
    }
#pragma unroll
    for (int mi = 0; mi < 4; ++mi) {
#pragma unroll
        for (int ni = 0; ni < 4; ++ni) {
#pragma unroll
            for (int r = 0; r < 4; ++r) {
                const int m = m0 + wr * 64 + mi * 16 + l4 * 4 + r;
                const int n = n0 + wc * 64 + ni * 16 + l15;
                const float v = acc[mi][ni][r];
                if (EPI == 0) {
                    const int b = m >> 10, s = m & 1023, h = n >> 6, d = n & 63;
                    ((unsigned short*)Cp)[(((size_t)b * H_ + h) * S_ + s) * D_ + d] = f2bf(v);
                } else if (EPI == 2) {
                    const int b = m >> 10, s = m & 1023, h = n >> 6, d = n & 63;
                    ((unsigned short*)Cp)[(((size_t)b * H_ + h) * D_ + d) * S_ + s] = f2bf(v);
                } else {
                    const size_t idx = (size_t)m * E_ + n;
                    ((float*)Cp)[idx] = v + resid[idx];
                }
            }
        }
    }
}

// ---------------- flash attention -------------------------------------------
__global__ __launch_bounds__(256) void attn_kernel(const unsigned short* __restrict__ Qh,
                                                   const unsigned short* __restrict__ Kh,
                                                   const unsigned short* __restrict__ Vt,
                                                   const unsigned long long* __restrict__ mbits,
                                                   unsigned short* __restrict__ degree) {
    __shared__ unsigned short Ks[64 * 64];
    __shared__ unsigned short Vs[64 * 64];
    __shared__ unsigned short Ps[4 * 16 * 64];
    const int t = threadIdx.x;
    const int lane = t & 63, w = t >> 6;
    const int l15 = lane & 15, l4 = lane >> 4;
    const int bh = blockIdx.y, b = bh >> 4, h = bh & 15;
    const int q0 = blockIdx.x * 64;

    const unsigned long long* mrow =
        mbits + ((size_t)b * S_ + q0 + w * 16 + l4 * 4) * NW_;

    bf16x8 qf[2];
    {
        const unsigned short* qptr =
            Qh + ((size_t)bh * S_ + q0 + w * 16 + l15) * D_ + l4 * 8;
        qf[0] = *(const bf16x8*)qptr;
        qf[1] = *(const bf16x8*)(qptr + 32);
    }
    f32x4 O[4];
#pragma unroll
    for (int i = 0; i < 4; ++i) O[i] = (f32x4){0.f, 0.f, 0.f, 0.f};
    float mrun[4] = {-3e38f, -3e38f, -3e38f, -3e38f};
    float lrun[4] = {0.f, 0.f, 0.f, 0.f};

    const int srow = t >> 2, sch = (t & 3) * 2;
    const int ssw = (srow & 7) << 4;
    char* KsB = (char*)Ks;
    char* VsB = (char*)Vs;
    char* PsB = (char*)Ps + w * 2048;

    for (int jt = 0; jt < S_; jt += 64) {
        {
            const unsigned short* kg =
                Kh + ((size_t)bh * S_ + jt + srow) * D_ + sch * 8;
            *(ushort8*)(KsB + srow * 128 + ((sch * 16) ^ ssw)) = *(const ushort8*)kg;
            *(ushort8*)(KsB + srow * 128 + ((sch * 16 + 16) ^ ssw)) = *(const ushort8*)(kg + 8);
            const unsigned short* vg =
                Vt + ((size_t)bh * D_ + srow) * S_ + jt + sch * 8;
            *(ushort8*)(VsB + srow * 128 + ((sch * 16) ^ ssw)) = *(const ushort8*)vg;
            *(ushort8*)(VsB + srow * 128 + ((sch * 16 + 16) ^ ssw)) = *(const ushort8*)(vg + 8);
        }
        const int mw_idx = jt >> 6;
        unsigned long long mw0 = mrow[0 * NW_ + mw_idx];
        unsigned long long mw1 = mrow[1 * NW_ + mw_idx];
        unsigned long long mw2 = mrow[2 * NW_ + mw_idx];
        unsigned long long mw3 = mrow[3 * NW_ + mw_idx];
        __syncthreads();

        f32x4 sacc[4];
#pragma unroll
        for (int i = 0; i < 4; ++i) sacc[i] = (f32x4){0.f, 0.f, 0.f, 0.f};
#pragma unroll
        for (int ni = 0; ni < 4; ++ni) {
            const int row = l15 + ni * 16;
            const int sw = (row & 7) << 4;
            bf16x8 b0 = *(const bf16x8*)(KsB + row * 128 + ((l4 * 16) ^ sw));
            bf16x8 b1 = *(const bf16x8*)(KsB + row * 128 + ((64 + l4 * 16) ^ sw));
            sacc[ni] = __builtin_amdgcn_mfma_f32_16x16x32_bf16(qf[0], b0, sacc[ni], 0, 0, 0);
            sacc[ni] = __builtin_amdgcn_mfma_f32_16x16x32_bf16(qf[1], b1, sacc[ni], 0, 0, 0);
        }

        float pv[4][4];
        unsigned long long mwr[4] = {mw0, mw1, mw2, mw3};
#pragma unroll
        for (int r = 0; r < 4; ++r) {
            const unsigned long long mw = mwr[r];
            float rowmax = -3e38f;
#pragma unroll
            for (int ni = 0; ni < 4; ++ni) {
                const int gc = l15 + ni * 16;
                const bool msk = (mw >> gc) & 1ull;
                const float s = msk ? -1e9f : sacc[ni][r] * 0.125f;
                pv[ni][r] = s;
                rowmax = fmaxf(rowmax, s);
            }
#pragma unroll
            for (int off = 1; off < 16; off <<= 1)
                rowmax = fmaxf(rowmax, __shfl_xor(rowmax, off, 64));
            const float mnew = fmaxf(mrun[r], rowmax);
            const float corr = __expf(mrun[r] - mnew);
            float ps = 0.f;
#pragma unroll
            for (int ni = 0; ni < 4; ++ni) {
                const float p = __expf(pv[ni][r] - mnew);
                pv[ni][r] = p;
                ps += p;
            }
#pragma unroll
            for (int off = 1; off < 16; off <<= 1) ps += __shfl_xor(ps, off, 64);
            lrun[r] = lrun[r] * corr + ps;
            mrun[r] = mnew;
#pragma unroll
            for (int df = 0; df < 4; ++df) O[df][r] *= corr;
        }

#pragma unroll
        for (int r = 0; r < 4; ++r) {
            const int row = l4 * 4 + r;
            const int sw = (row & 7) << 4;
#pragma unroll
            for (int ni = 0; ni < 4; ++ni) {
                const int col = l15 + ni * 16;
                *(unsigned short*)(PsB + row * 128 + ((col * 2) ^ sw)) = f2bf(pv[ni][r]);
            }
        }
        asm volatile("s_waitcnt lgkmcnt(0)" ::: "memory");
        bf16x8 pa[2];
        {
            const int row = l15;
            const int sw = (row & 7) << 4;
            pa[0] = *(const bf16x8*)(PsB + row * 128 + ((l4 * 16) ^ sw));
            pa[1] = *(const bf16x8*)(PsB + row * 128 + ((64 + l4 * 16) ^ sw));
        }
#pragma unroll
        for (int df = 0; df < 4; ++df) {
            const int row = l15 + df * 16;
            const int sw = (row & 7) << 4;
            bf16x8 v0 = *(const bf16x8*)(VsB + row * 128 + ((l4 * 16) ^ sw));
            bf16x8 v1 = *(const bf16x8*)(VsB + row * 128 + ((64 + l4 * 16) ^ sw));
            O[df] = __builtin_amdgcn_mfma_f32_16x16x32_bf16(pa[0], v0, O[df], 0, 0, 0);
            O[df] = __builtin_amdgcn_mfma_f32_16x16x32_bf16(pa[1], v1, O[df], 0, 0, 0);
        }
        __syncthreads();
    }

#pragma unroll
    for (int r = 0; r < 4; ++r) {
        const float inv = 1.f / lrun[r];
#pragma unroll
        for (int df = 0; df < 4; ++df) {
            const size_t dst = ((size_t)b * S_ + q0 + w * 16 + l4 * 4 + r) * (size_t)(H_ * D_) +
                               h * 64 + df * 16 + l15;
            degree[dst] = f2bf(O[df][r] * inv);
        }
    }
}

// ---------------- in-place row LayerNorm over E=1024 ------------------------
__global__ __launch_bounds__(256) void lnorm(float* __restrict__ io,
                                             const float* __restrict__ gamma,
                                             const float* __restrict__ beta) {
    const int row = blockIdx.x;
    const int t = threadIdx.x;
    float4 v = ((const float4*)(io + (size_t)row * E_))[t];
    float s = v.x + v.y + v.z + v.w;
    float q = v.x * v.x + v.y * v.y + v.z * v.z + v.w * v.w;
#pragma unroll
    for (int off = 32; off; off >>= 1) {
        s += __shfl_down(s, off, 64);
        q += __shfl_down(q, off, 64);
    }
    __shared__ float red[8];
    const int wid = t >> 6;
    if ((t & 63) == 0) { red[wid] = s; red[4 + wid] = q; }
    __syncthreads();
    const float ts = red[0] + red[1] + red[2] + red[3];
    const float tq = red[4] + red[5] + red[6] + red[7];
    const float mean = ts * (1.0f / E_);
    const float var = tq * (1.0f / E_) - mean * mean;
    const float rstd = rsqrtf(var + 1e-5f);
    const float4 g = ((const float4*)gamma)[t];
    const float4 bb = ((const float4*)beta)[t];
    v.x = (v.x - mean) * rstd * g.x + bb.x;
    v.y = (v.y - mean) * rstd * g.y + bb.y;
    v.z = (v.z - mean) * rstd * g.z + bb.z;
    v.w = (v.w - mean) * rstd * g.w + bb.w;
    ((float4*)(io + (size_t)row * E_))[t] = v;
}

extern "C" void kernel_launch(void* const* d_in, const int* in_sizes, int n_in,
                              void* d_out, int out_size, void* d_ws, size_t ws_size,
                              hipStream_t stream) {
    const float* query = (const float*)d_in[0];
    const float* key_ = (const float*)d_in[1];
    const float* value = (const float*)d_in[2];
    const void* maskp = d_in[3];
    const float* Wq = (const float*)d_in[4];
    const float* Wk = (const float*)d_in[5];
    const float* Wv = (const float*)d_in[6];
    const float* Wo = (const float*)d_in[7];
    const float* gamma = (const float*)d_in[8];
    const float* beta = (const float*)d_in[9];
    float* out = (float*)d_out;
    char* ws = (char*)d_ws;
    const size_t MB = 1024ull * 1024ull;

    unsigned short* WqT = (unsigned short*)(ws + 0 * MB);
    unsigned short* WkT = (unsigned short*)(ws + 2 * MB);
    unsigned short* WvT = (unsigned short*)(ws + 4 * MB);
    unsigned short* WoT = (unsigned short*)(ws + 6 * MB);
    unsigned short* Qh = (unsigned short*)(ws + 8 * MB);   // [B,H,S,D] bf16 16MB
    unsigned short* Kh = (unsigned short*)(ws + 24 * MB);  // [B,H,S,D] bf16 16MB
    unsigned short* Vt = (unsigned short*)(ws + 40 * MB);  // [B,H,D,S] bf16 16MB
    unsigned short* deg = (unsigned short*)(ws + 56 * MB); // [B,S,H*D] bf16 16MB
    unsigned short* Abf = deg;  // bf16 A staging; dead once attn writes deg
    int* flag = (int*)(ws + 72 * MB);
    unsigned long long* mbits = (unsigned long long*)(ws + 72 * MB + 4096);  // 1MB

    const int n8 = B_ * S_ * E_ / 8;

    wtrans<<<dim3(32, 32), 256, 0, stream>>>(Wq, WqT);
    wtrans<<<dim3(32, 32), 256, 0, stream>>>(Wk, WkT);
    wtrans<<<dim3(32, 32), 256, 0, stream>>>(Wv, WvT);
    wtrans<<<dim3(32, 32), 256, 0, stream>>>(Wo, WoT);
    detect_kernel<<<1, 64, 0, stream>>>((const unsigned int*)maskp, flag);
    pack_mask<<<2048, 256, 0, stream>>>(maskp, flag, mbits);

    f32_to_bf16<<<2048, 256, 0, stream>>>(query, Abf, n8);
    gemm_bt<0><<<dim3(64, 8), 256, 0, stream>>>(Abf, WqT, Qh, nullptr);
    f32_to_bf16<<<2048, 256, 0, stream>>>(key_, Abf, n8);
    gemm_bt<0><<<dim3(64, 8), 256, 0, stream>>>(Abf, WkT, Kh, nullptr);
    f32_to_bf16<<<2048, 256, 0, stream>>>(value, Abf, n8);
    gemm_bt<2><<<dim3(64, 8), 256, 0, stream>>>(Abf, WvT, Vt, nullptr);

    attn_kernel<<<dim3(16, 128), 256, 0, stream>>>(Qh, Kh, Vt, mbits, deg);

    gemm_bt<3><<<dim3(64, 8), 256, 0, stream>>>(deg, WoT, out, query);
    lnorm<<<8192, 256, 0, stream>>>(out, gamma, beta);
}